// Round 18
// baseline (151.253 us; speedup 1.0000x reference)
//
#include <hip/hip_runtime.h>
#include <stdint.h>

typedef short bf16x8 __attribute__((ext_vector_type(8)));
typedef float f32x4 __attribute__((ext_vector_type(4)));
typedef float f32x16 __attribute__((ext_vector_type(16)));

#define MFMA16(a, b, c) __builtin_amdgcn_mfma_f32_16x16x32_bf16((a), (b), (c), 0, 0, 0)
#define MFMA32(a, b, c) __builtin_amdgcn_mfma_f32_32x32x16_bf16((a), (b), (c), 0, 0, 0)

__device__ __forceinline__ unsigned short f2bf(float x) {
  union { float f; unsigned int u; } v; v.f = x;
  unsigned int r = (v.u + 0x7FFFu + ((v.u >> 16) & 1u)) >> 16;
  return (unsigned short)r;
}

__device__ __forceinline__ unsigned int cvtpk(float lo, float hi) {
  unsigned int r;
  asm("v_cvt_pk_bf16_f32 %0, %1, %2" : "=v"(r) : "v"(lo), "v"(hi));
  return r;
}

__device__ __forceinline__ void plswap(unsigned int& a, unsigned int& b) {
  asm("v_permlane32_swap_b32 %0, %1" : "+v"(a), "+v"(b));
}

__device__ __forceinline__ float exp2f_fast(float x) {
  float r;
  asm("v_exp_f32 %0, %1" : "=v"(r) : "v"(x));
  return r;
}

// ---------------------------------------------------------------- merged convert
__global__ void __launch_bounds__(256) cvt_all(const float* __restrict__ x,
                                               const float* __restrict__ Wk,
                                               const float* __restrict__ Wq,
                                               const float* __restrict__ Wv,
                                               const float* __restrict__ Wp,
                                               unsigned short* __restrict__ xb,
                                               unsigned short* __restrict__ wqkvb,
                                               unsigned short* __restrict__ wpb) {
  const int stride = gridDim.x * blockDim.x;
  for (int i = blockIdx.x * blockDim.x + threadIdx.x; i < 3145728; i += stride) {
    if (i < 2097152) {
      float4 v = ((const float4*)x)[i];
      ushort4 o;
      o.x = f2bf(v.x); o.y = f2bf(v.y); o.z = f2bf(v.z); o.w = f2bf(v.w);
      ((ushort4*)xb)[i] = o;
      continue;
    }
    int j = i - 2097152;
    int sec = j >> 18;  // 0=Wk 1=Wq 2=Wv 3=Wp
    int off = j & 262143;
    const float4* s4 = (const float4*)(sec == 0 ? Wk : sec == 1 ? Wq : sec == 2 ? Wv : Wp);
    float4 v = s4[off];
    ushort4 o;
    o.x = f2bf(v.x); o.y = f2bf(v.y); o.z = f2bf(v.z); o.w = f2bf(v.w);
    if (sec < 3) ((ushort4*)wqkvb)[j] = o;
    else ((ushort4*)wpb)[off] = o;
  }
}

// ---------------------------------------------------------------- 8-phase QKV GEMM, 256x192 (R17-exact)
__global__ void __launch_bounds__(512) gemm_qkv8(const unsigned short* __restrict__ A,
                                                 const unsigned short* __restrict__ Bw,
                                                 const float* __restrict__ b0,
                                                 const float* __restrict__ b1,
                                                 const float* __restrict__ b2,
                                                 unsigned short* __restrict__ O0,
                                                 unsigned short* __restrict__ O1,
                                                 unsigned short* __restrict__ O2) {
  extern __shared__ unsigned short lds[];
#define HBASE(buf, isB, kk) \
  (lds + ((isB) ? (32768 + (buf)*12288 + (kk)*6144) : ((buf)*16384 + (kk)*8192)))

  const int tid = threadIdx.x;
  const int wid = tid >> 6;
  const int l = tid & 63;
  const int g = l >> 4;
  const int ln = l & 15;

  const int bid = blockIdx.x;
  const int swz = (bid & 7) * 64 + (bid >> 3);  // bijective: 512 = 8*64
  const int bx = swz & 15;
  const int by = swz >> 4;
  const int m0 = by * 256;
  const int n0 = bx * 192;
  const int wm = (wid >> 2) * 128;
  const int wn = (wid & 3) * 48;

  f32x4 acc[8][3];
#pragma unroll
  for (int i = 0; i < 8; ++i)
#pragma unroll
    for (int j = 0; j < 3; ++j) acc[i][j] = (f32x4){0.f, 0.f, 0.f, 0.f};

#define STAGEA(buf, kk, kt)                                                                       \
  {                                                                                               \
    unsigned short* dst = HBASE(buf, 0, kk);                                                      \
    _Pragma("unroll") for (int i = 0; i < 2; ++i) {                                               \
      int c = i * 512 + tid;                                                                      \
      int r = c >> 2;                                                                             \
      int x = (c & 3) ^ ((r >> 1) & 3);                                                           \
      const unsigned short* gp = A + (size_t)(m0 + r) * 1024 + (kt) + (kk)*32 + x * 8;            \
      __builtin_amdgcn_global_load_lds((const __attribute__((address_space(1))) void*)gp,         \
                                       (__attribute__((address_space(3))) void*)&dst[c * 8],      \
                                       16, 0, 0);                                                 \
    }                                                                                             \
  }
#define STAGEB(buf, kk, kt)                                                                       \
  {                                                                                               \
    unsigned short* dst = HBASE(buf, 1, kk);                                                      \
    _Pragma("unroll") for (int i = 0; i < 2; ++i) {                                               \
      int c = (i == 0) ? tid : (512 + (tid & 255));                                               \
      int r = c >> 2;                                                                             \
      int x = (c & 3) ^ ((r >> 1) & 3);                                                           \
      const unsigned short* gp = Bw + (size_t)(n0 + r) * 1024 + (kt) + (kk)*32 + x * 8;           \
      __builtin_amdgcn_global_load_lds((const __attribute__((address_space(1))) void*)gp,         \
                                       (__attribute__((address_space(3))) void*)&dst[c * 8],      \
                                       16, 0, 0);                                                 \
    }                                                                                             \
  }

  STAGEA(0, 0, 0);
  STAGEB(0, 0, 0);
  STAGEA(0, 1, 0);
  STAGEB(0, 1, 0);

  for (int T = 0; T < 16; ++T) {
    const int buf = T & 1;
    const int last = (T == 15);
    bf16x8 bF[3];
#pragma unroll
    for (int ph = 0; ph < 4; ++ph) {
      const int kk = ph >> 1;
      const int mg = ph & 1;

      if (mg == 0) {
        if (!last) asm volatile("s_waitcnt vmcnt(4)" ::: "memory");
        else asm volatile("s_waitcnt vmcnt(0)" ::: "memory");
      }
      if (!last) {
        if (ph == 0) STAGEA(buf ^ 1, 0, (T + 1) * 64);
        if (ph == 1) STAGEB(buf ^ 1, 0, (T + 1) * 64);
        if (ph == 2) STAGEA(buf ^ 1, 1, (T + 1) * 64);
        if (ph == 3) STAGEB(buf ^ 1, 1, (T + 1) * 64);
      }
      if (mg == 0) {
        __builtin_amdgcn_sched_barrier(0);
        __builtin_amdgcn_s_barrier();
        __builtin_amdgcn_sched_barrier(0);
#pragma unroll
        for (int ni = 0; ni < 3; ++ni) {
          int rb = wn + ni * 16 + ln;
          bF[ni] = *(const bf16x8*)&HBASE(buf, 1, kk)[rb * 32 + (g ^ ((rb >> 1) & 3)) * 8];
        }
      }
      bf16x8 aF[4];
#pragma unroll
      for (int j = 0; j < 4; ++j) {
        int ra = wm + (mg * 4 + j) * 16 + ln;
        aF[j] = *(const bf16x8*)&HBASE(buf, 0, kk)[ra * 32 + (g ^ ((ra >> 1) & 3)) * 8];
      }
      __builtin_amdgcn_s_setprio(1);
#pragma unroll
      for (int j = 0; j < 4; ++j)
#pragma unroll
        for (int ni = 0; ni < 3; ++ni)
          acc[mg * 4 + j][ni] = MFMA16(aF[j], bF[ni], acc[mg * 4 + j][ni]);
      __builtin_amdgcn_s_setprio(0);
      if (ph == 3) {
        __builtin_amdgcn_sched_barrier(0);
        __builtin_amdgcn_s_barrier();
        __builtin_amdgcn_sched_barrier(0);
      }
    }
  }
#undef STAGEA
#undef STAGEB
#undef HBASE

  const int mBase = m0 + wm + g * 4;
  const int nBase = n0 + wn + ln;
#pragma unroll
  for (int mi = 0; mi < 8; ++mi) {
    int mg2 = mBase + mi * 16;
    int b = mg2 >> 11, t = mg2 & 2047;
#pragma unroll
    for (int ni = 0; ni < 3; ++ni) {
      int n = nBase + ni * 16;
      int sec = n >> 10;
      int nn = n & 1023;
      int h = nn >> 6, d = nn & 63;
      const float* bias = (sec == 0) ? b0 : (sec == 1) ? b1 : b2;
      float bvl = bias[nn];
      if (sec == 2) {
        ushort4 pk;
        pk.x = f2bf(acc[mi][ni][0] + bvl);
        pk.y = f2bf(acc[mi][ni][1] + bvl);
        pk.z = f2bf(acc[mi][ni][2] + bvl);
        pk.w = f2bf(acc[mi][ni][3] + bvl);
        *(ushort4*)&O2[((size_t)((b * 16 + h) * 64 + d)) * 2048 + t] = pk;
      } else {
        unsigned short* O = sec ? O1 : O0;
        const float sc = sec ? (0.125f * 1.44269504f) : 1.0f;
#pragma unroll
        for (int r = 0; r < 4; ++r)
          O[((size_t)(b * 16 + h) * 2048 + (t + r)) * 64 + d] = f2bf((acc[mi][ni][r] + bvl) * sc);
      }
    }
  }
}

// ---------------------------------------------------------------- 8-phase proj GEMM, 256x128
// 256 blocks = 1 exact round. LDS 96 KiB: A halves [256][32] x2kk x2buf,
// B halves [128][32] x2kk x2buf. Wave 128x32 (2M x 4N), acc 8x2 (64 VGPR).
// Per-thread loads: A=2, B=1 per half -> T total 6; vmcnt(3) at ph0/ph2
// (leaves exactly the 3 not-yet-needed loads in flight); tail vmcnt(0).
__global__ void __launch_bounds__(512) gemm_proj8(const unsigned short* __restrict__ A,
                                                  const unsigned short* __restrict__ Bw,
                                                  const float* __restrict__ b0,
                                                  float* __restrict__ Of) {
  extern __shared__ unsigned short lds[];
#define HBASE(buf, isB, kk) \
  (lds + ((isB) ? (32768 + (buf)*8192 + (kk)*4096) : ((buf)*16384 + (kk)*8192)))

  const int tid = threadIdx.x;
  const int wid = tid >> 6;
  const int l = tid & 63;
  const int g = l >> 4;
  const int ln = l & 15;

  const int bid = blockIdx.x;
  const int swz = (bid & 7) * 32 + (bid >> 3);  // bijective: 256 = 8*32
  const int bx = swz & 7;                       // N tiles: 1024/128 = 8
  const int by = swz >> 3;                      // M tiles: 32
  const int m0 = by * 256;
  const int n0 = bx * 128;
  const int wm = (wid >> 2) * 128;
  const int wn = (wid & 3) * 32;

  f32x4 acc[8][2];
#pragma unroll
  for (int i = 0; i < 8; ++i)
#pragma unroll
    for (int j = 0; j < 2; ++j) acc[i][j] = (f32x4){0.f, 0.f, 0.f, 0.f};

#define STAGEA(buf, kk, kt)                                                                       \
  {                                                                                               \
    unsigned short* dst = HBASE(buf, 0, kk);                                                      \
    _Pragma("unroll") for (int i = 0; i < 2; ++i) {                                               \
      int c = i * 512 + tid;                                                                      \
      int r = c >> 2;                                                                             \
      int x = (c & 3) ^ ((r >> 1) & 3);                                                           \
      const unsigned short* gp = A + (size_t)(m0 + r) * 1024 + (kt) + (kk)*32 + x * 8;            \
      __builtin_amdgcn_global_load_lds((const __attribute__((address_space(1))) void*)gp,         \
                                       (__attribute__((address_space(3))) void*)&dst[c * 8],      \
                                       16, 0, 0);                                                 \
    }                                                                                             \
  }
#define STAGEB(buf, kk, kt)                                                                       \
  {                                                                                               \
    unsigned short* dst = HBASE(buf, 1, kk);                                                      \
    {                                                                                             \
      int c = tid;                                                                                \
      int r = c >> 2;                                                                             \
      int x = (c & 3) ^ ((r >> 1) & 3);                                                           \
      const unsigned short* gp = Bw + (size_t)(n0 + r) * 1024 + (kt) + (kk)*32 + x * 8;           \
      __builtin_amdgcn_global_load_lds((const __attribute__((address_space(1))) void*)gp,         \
                                       (__attribute__((address_space(3))) void*)&dst[c * 8],      \
                                       16, 0, 0);                                                 \
    }                                                                                             \
  }

  STAGEA(0, 0, 0);
  STAGEB(0, 0, 0);
  STAGEA(0, 1, 0);
  STAGEB(0, 1, 0);

  for (int T = 0; T < 16; ++T) {
    const int buf = T & 1;
    const int last = (T == 15);
    bf16x8 bF[2];
#pragma unroll
    for (int ph = 0; ph < 4; ++ph) {
      const int kk = ph >> 1;
      const int mg = ph & 1;

      if (mg == 0) {
        if (!last) asm volatile("s_waitcnt vmcnt(3)" ::: "memory");
        else asm volatile("s_waitcnt vmcnt(0)" ::: "memory");
      }
      if (!last) {
        if (ph == 0) STAGEA(buf ^ 1, 0, (T + 1) * 64);
        if (ph == 1) STAGEB(buf ^ 1, 0, (T + 1) * 64);
        if (ph == 2) STAGEA(buf ^ 1, 1, (T + 1) * 64);
        if (ph == 3) STAGEB(buf ^ 1, 1, (T + 1) * 64);
      }
      if (mg == 0) {
        __builtin_amdgcn_sched_barrier(0);
        __builtin_amdgcn_s_barrier();
        __builtin_amdgcn_sched_barrier(0);
#pragma unroll
        for (int ni = 0; ni < 2; ++ni) {
          int rb = wn + ni * 16 + ln;
          bF[ni] = *(const bf16x8*)&HBASE(buf, 1, kk)[rb * 32 + (g ^ ((rb >> 1) & 3)) * 8];
        }
      }
      bf16x8 aF[4];
#pragma unroll
      for (int j = 0; j < 4; ++j) {
        int ra = wm + (mg * 4 + j) * 16 + ln;
        aF[j] = *(const bf16x8*)&HBASE(buf, 0, kk)[ra * 32 + (g ^ ((ra >> 1) & 3)) * 8];
      }
      __builtin_amdgcn_s_setprio(1);
#pragma unroll
      for (int j = 0; j < 4; ++j)
#pragma unroll
        for (int ni = 0; ni < 2; ++ni)
          acc[mg * 4 + j][ni] = MFMA16(aF[j], bF[ni], acc[mg * 4 + j][ni]);
      __builtin_amdgcn_s_setprio(0);
      if (ph == 3) {
        __builtin_amdgcn_sched_barrier(0);
        __builtin_amdgcn_s_barrier();
        __builtin_amdgcn_sched_barrier(0);
      }
    }
  }
#undef STAGEA
#undef STAGEB
#undef HBASE

  const int mBase = m0 + wm + g * 4;
  const int nBase = n0 + wn + ln;
#pragma unroll
  for (int mi = 0; mi < 8; ++mi) {
    int mg2 = mBase + mi * 16;
#pragma unroll
    for (int ni = 0; ni < 2; ++ni) {
      int n = nBase + ni * 16;
      float bvl = b0[n];
#pragma unroll
      for (int r = 0; r < 4; ++r) Of[(size_t)(mg2 + r) * 1024 + n] = acc[mi][ni][r] + bvl;
    }
  }
}

// ---------------------------------------------------------------- attention (R13-exact)
__global__ void __launch_bounds__(512) attn_kernel(const unsigned short* __restrict__ Q,
                                                   const unsigned short* __restrict__ K,
                                                   const unsigned short* __restrict__ Vt,
                                                   unsigned short* __restrict__ Y) {
  __shared__ unsigned short Ks[2][64 * 64];
  __shared__ unsigned short Vs[2][64 * 64];

  const int tid = threadIdx.x;
  const int wid = tid >> 6;          // 0..7
  const int l = tid & 63;
  const int q32 = l & 31;
  const int hi = l >> 5;
  const int bh = blockIdx.x & 63;
  const int u = blockIdx.x >> 6;     // 0..7
  const int j = (u < 4) ? u : (11 - u);
  const int qblk = (wid < 4) ? (15 - j) : j;
  const int q0w = qblk * 128 + (wid & 3) * 32;
  const int NT = 2 * (15 - j) + 2;
  const int myNt = (q0w + 95) >> 6;

  const unsigned short* Qp = Q + (size_t)bh * 2048 * 64;
  const unsigned short* Kp = K + (size_t)bh * 2048 * 64;
  const unsigned short* Vp = Vt + (size_t)bh * 64 * 2048;
  const int b = bh >> 4, h = bh & 15;

  const int srow = tid >> 3;
  const int csw = (tid & 7) ^ (srow & 7);

  bf16x8 qf[4];
#pragma unroll
  for (int kk = 0; kk < 4; ++kk)
    qf[kk] = *(const bf16x8*)&Qp[(size_t)(q0w + q32) * 64 + kk * 16 + hi * 8];

  f32x16 o0, o1;
#pragma unroll
  for (int r = 0; r < 16; ++r) { o0[r] = 0.f; o1[r] = 0.f; }
  float m = -1e30f, lst = 0.f;

#define STAGE(bufi, kk0)                                                                        \
  {                                                                                             \
    const unsigned short* gk = Kp + (size_t)((kk0) + srow) * 64 + csw * 8;                      \
    const unsigned short* gv = Vp + (size_t)srow * 2048 + (kk0) + csw * 8;                      \
    __builtin_amdgcn_global_load_lds((const __attribute__((address_space(1))) void*)gk,         \
                                     (__attribute__((address_space(3))) void*)                  \
                                         &Ks[bufi][wid * 512],                                  \
                                     16, 0, 0);                                                 \
    __builtin_amdgcn_global_load_lds((const __attribute__((address_space(1))) void*)gv,         \
                                     (__attribute__((address_space(3))) void*)                  \
                                         &Vs[bufi][wid * 512],                                  \
                                     16, 0, 0);                                                 \
  }

  int buf = 0;
  STAGE(0, 0);
  __syncthreads();

  for (int t = 0; t < NT; ++t) {
    const int k0 = t * 64;
    if (t + 1 < NT) STAGE(buf ^ 1, k0 + 64);

    if (t < myNt) {
      const int xr = q32 & 7;
      f32x16 s0, s1;
#pragma unroll
      for (int r = 0; r < 16; ++r) { s0[r] = 0.f; s1[r] = 0.f; }
      __builtin_amdgcn_s_setprio(1);
#pragma unroll
      for (int kk = 0; kk < 4; ++kk) {
        bf16x8 kf0 = *(const bf16x8*)&Ks[buf][q32 * 64 + (((kk << 1) | hi) ^ xr) * 8];
        bf16x8 kf1 = *(const bf16x8*)&Ks[buf][(32 + q32) * 64 + (((kk << 1) | hi) ^ xr) * 8];
        s0 = MFMA32(kf0, qf[kk], s0);
        s1 = MFMA32(kf1, qf[kk], s1);
      }
      __builtin_amdgcn_s_setprio(0);

      if (k0 + 63 > q0w) {
        const int qg = q0w + q32;
#pragma unroll
        for (int r = 0; r < 16; ++r) {
          int kr = (r & 3) + 8 * (r >> 2) + 4 * hi;
          if (k0 + kr > qg) s0[r] = -1e30f;
          if (k0 + 32 + kr > qg) s1[r] = -1e30f;
        }
      }

      float pm = fmaxf(fmaxf(s0[0], s0[1]), s0[2]);
#pragma unroll
      for (int r = 3; r < 15; r += 3) pm = fmaxf(fmaxf(fmaxf(s0[r], s0[r + 1]), s0[r + 2]), pm);
      pm = fmaxf(pm, s0[15]);
#pragma unroll
      for (int r = 0; r < 15; r += 3) pm = fmaxf(fmaxf(fmaxf(s1[r], s1[r + 1]), s1[r + 2]), pm);
      pm = fmaxf(pm, s1[15]);
      pm = fmaxf(pm, __shfl_xor(pm, 32));

      if (__any(pm > m + 11.0f)) {
        float mn = fmaxf(m, pm);
        float sf = exp2f_fast(m - mn);
        m = mn;
        lst *= sf;
#pragma unroll
        for (int r = 0; r < 16; ++r) {
          float sb2 = __shfl(sf, (r & 3) + 8 * (r >> 2) + 4 * hi);
          o0[r] *= sb2;
          o1[r] *= sb2;
        }
      }
      float rs = 0.f;
#pragma unroll
      for (int r = 0; r < 16; ++r) { s0[r] = exp2f_fast(s0[r] - m); rs += s0[r]; }
#pragma unroll
      for (int r = 0; r < 16; ++r) { s1[r] = exp2f_fast(s1[r] - m); rs += s1[r]; }
      rs += __shfl_xor(rs, 32);
      lst += rs;

      union { unsigned int u[4]; bf16x8 v; } pa[4];
#pragma unroll
      for (int t2 = 0; t2 < 2; ++t2) {
        const f32x16& sv = t2 ? s1 : s0;
#pragma unroll
        for (int sl = 0; sl < 2; ++sl) {
          int base = sl * 8;
          unsigned int x0 = cvtpk(sv[base + 0], sv[base + 1]);
          unsigned int x1 = cvtpk(sv[base + 2], sv[base + 3]);
          unsigned int x2 = cvtpk(sv[base + 4], sv[base + 5]);
          unsigned int x3 = cvtpk(sv[base + 6], sv[base + 7]);
          plswap(x0, x2);
          plswap(x1, x3);
          int ksg = t2 * 2 + sl;
          pa[ksg].u[0] = x0; pa[ksg].u[1] = x1; pa[ksg].u[2] = x2; pa[ksg].u[3] = x3;
        }
      }

      __builtin_amdgcn_s_setprio(1);
#pragma unroll
      for (int ksg = 0; ksg < 4; ++ksg) {
        bf16x8 v0 = *(const bf16x8*)&Vs[buf][q32 * 64 + (((ksg << 1) | hi) ^ xr) * 8];
        bf16x8 v1 = *(const bf16x8*)&Vs[buf][(32 + q32) * 64 + (((ksg << 1) | hi) ^ xr) * 8];
        o0 = MFMA32(pa[ksg].v, v0, o0);
        o1 = MFMA32(pa[ksg].v, v1, o1);
      }
      __builtin_amdgcn_s_setprio(0);
    }

    __syncthreads();
    buf ^= 1;
  }

#pragma unroll
  for (int r = 0; r < 16; ++r) {
    int qsrc = (r & 3) + 8 * (r >> 2) + 4 * hi;
    int qg = q0w + qsrc;
    float lq = __shfl(lst, qsrc);
    float inv = 1.0f / lq;
    size_t rowb = (size_t)(b * 2048 + qg) * 1024 + h * 64;
    Y[rowb + q32] = f2bf(o0[r] * inv);
    Y[rowb + 32 + q32] = f2bf(o1[r] * inv);
  }
#undef STAGE
}

// ---------------------------------------------------------------- launch
extern "C" void kernel_launch(void* const* d_in, const int* in_sizes, int n_in,
                              void* d_out, int out_size, void* d_ws, size_t ws_size,
                              hipStream_t stream) {
  const float* x = (const float*)d_in[0];
  const float* Wk = (const float*)d_in[1];
  const float* bk = (const float*)d_in[2];
  const float* Wq = (const float*)d_in[3];
  const float* bq = (const float*)d_in[4];
  const float* Wv = (const float*)d_in[5];
  const float* bv = (const float*)d_in[6];
  const float* Wp = (const float*)d_in[7];
  const float* bp = (const float*)d_in[8];
  float* out = (float*)d_out;

  char* ws = (char*)d_ws;
  unsigned short* xb    = (unsigned short*)(ws);                 // 16 MiB [8192,1024]
  unsigned short* wqkvb = (unsigned short*)(ws + 16777216);      // 6 MiB  [3072,1024]
  unsigned short* wpb   = (unsigned short*)(ws + 23068672);      // 2 MiB
  unsigned short* Qb    = (unsigned short*)(ws + 25165824);      // 16 MiB [B,H,T,D]
  unsigned short* Kb    = (unsigned short*)(ws + 41943040);      // 16 MiB [B,H,T,D]
  unsigned short* Vtb   = (unsigned short*)(ws + 58720256);      // 16 MiB [B,H,D,T]
  unsigned short* yb    = (unsigned short*)(ws + 75497472);      // 16 MiB [M,1024]
  if (ws_size < 92274688u) return;

  const int LDS_Q = 114688;  // 112 KiB (8-phase 256x192)
  const int LDS_P = 98304;   // 96 KiB (8-phase 256x128)
  (void)hipFuncSetAttribute((const void*)&gemm_qkv8,
                            hipFuncAttributeMaxDynamicSharedMemorySize, LDS_Q);
  (void)hipFuncSetAttribute((const void*)&gemm_proj8,
                            hipFuncAttributeMaxDynamicSharedMemorySize, LDS_P);

  cvt_all<<<dim3(3072), dim3(256), 0, stream>>>(x, Wk, Wq, Wv, Wp, xb, wqkvb, wpb);

  // QKV: 32 m-tiles x 16 n-tiles (256x192) -> 512 blocks = 2 exact rounds
  gemm_qkv8<<<dim3(512), dim3(512), LDS_Q, stream>>>(xb, wqkvb, bk, bq, bv, Kb, Qb, Vtb);

  attn_kernel<<<dim3(512), dim3(512), 0, stream>>>(Qb, Kb, Vtb, yb);

  // proj: 32 m-tiles x 8 n-tiles (256x128) -> 256 blocks = 1 exact round
  gemm_proj8<<<dim3(256), dim3(512), LDS_P, stream>>>(yb, wpb, bp, out);
}

// Round 19
// 150.277 us; speedup vs baseline: 1.0065x; 1.0065x over previous
//
#include <hip/hip_runtime.h>
#include <stdint.h>

typedef short bf16x8 __attribute__((ext_vector_type(8)));
typedef float f32x4 __attribute__((ext_vector_type(4)));
typedef float f32x16 __attribute__((ext_vector_type(16)));

#define MFMA16(a, b, c) __builtin_amdgcn_mfma_f32_16x16x32_bf16((a), (b), (c), 0, 0, 0)
#define MFMA32(a, b, c) __builtin_amdgcn_mfma_f32_32x32x16_bf16((a), (b), (c), 0, 0, 0)

__device__ __forceinline__ unsigned short f2bf(float x) {
  union { float f; unsigned int u; } v; v.f = x;
  unsigned int r = (v.u + 0x7FFFu + ((v.u >> 16) & 1u)) >> 16;
  return (unsigned short)r;
}

__device__ __forceinline__ unsigned int cvtpk(float lo, float hi) {
  unsigned int r;
  asm("v_cvt_pk_bf16_f32 %0, %1, %2" : "=v"(r) : "v"(lo), "v"(hi));
  return r;
}

__device__ __forceinline__ void plswap(unsigned int& a, unsigned int& b) {
  asm("v_permlane32_swap_b32 %0, %1" : "+v"(a), "+v"(b));
}

__device__ __forceinline__ float exp2f_fast(float x) {
  float r;
  asm("v_exp_f32 %0, %1" : "=v"(r) : "v"(x));
  return r;
}

// ---------------------------------------------------------------- merged convert
__global__ void __launch_bounds__(256) cvt_all(const float* __restrict__ x,
                                               const float* __restrict__ Wk,
                                               const float* __restrict__ Wq,
                                               const float* __restrict__ Wv,
                                               const float* __restrict__ Wp,
                                               unsigned short* __restrict__ xb,
                                               unsigned short* __restrict__ wqkvb,
                                               unsigned short* __restrict__ wpb) {
  const int stride = gridDim.x * blockDim.x;
  for (int i = blockIdx.x * blockDim.x + threadIdx.x; i < 3145728; i += stride) {
    if (i < 2097152) {
      float4 v = ((const float4*)x)[i];
      ushort4 o;
      o.x = f2bf(v.x); o.y = f2bf(v.y); o.z = f2bf(v.z); o.w = f2bf(v.w);
      ((ushort4*)xb)[i] = o;
      continue;
    }
    int j = i - 2097152;
    int sec = j >> 18;  // 0=Wk 1=Wq 2=Wv 3=Wp
    int off = j & 262143;
    const float4* s4 = (const float4*)(sec == 0 ? Wk : sec == 1 ? Wq : sec == 2 ? Wv : Wp);
    float4 v = s4[off];
    ushort4 o;
    o.x = f2bf(v.x); o.y = f2bf(v.y); o.z = f2bf(v.z); o.w = f2bf(v.w);
    if (sec < 3) ((ushort4*)wqkvb)[j] = o;
    else ((ushort4*)wpb)[off] = o;
  }
}

// ---------------------------------------------------------------- 8-phase QKV GEMM, 256x192
// 512 blocks = 2 EXACT rounds. LDS 112 KiB: A halves [256][32] x2kk x2buf,
// B halves [192][32] x2kk x2buf. 8 waves (2M x 4N; wave 128x48). Counted
// vmcnt(4): stage T+1 {A0,B0,A1,B1} across T's phases; never drain mid-loop.
__global__ void __launch_bounds__(512) gemm_qkv8(const unsigned short* __restrict__ A,
                                                 const unsigned short* __restrict__ Bw,
                                                 const float* __restrict__ b0,
                                                 const float* __restrict__ b1,
                                                 const float* __restrict__ b2,
                                                 unsigned short* __restrict__ O0,
                                                 unsigned short* __restrict__ O1,
                                                 unsigned short* __restrict__ O2) {
  extern __shared__ unsigned short lds[];
#define HBASE(buf, isB, kk) \
  (lds + ((isB) ? (32768 + (buf)*12288 + (kk)*6144) : ((buf)*16384 + (kk)*8192)))

  const int tid = threadIdx.x;
  const int wid = tid >> 6;
  const int l = tid & 63;
  const int g = l >> 4;
  const int ln = l & 15;

  const int bid = blockIdx.x;
  const int swz = (bid & 7) * 64 + (bid >> 3);  // bijective: 512 = 8*64
  const int bx = swz & 15;
  const int by = swz >> 4;
  const int m0 = by * 256;
  const int n0 = bx * 192;
  const int wm = (wid >> 2) * 128;
  const int wn = (wid & 3) * 48;

  f32x4 acc[8][3];
#pragma unroll
  for (int i = 0; i < 8; ++i)
#pragma unroll
    for (int j = 0; j < 3; ++j) acc[i][j] = (f32x4){0.f, 0.f, 0.f, 0.f};

#define STAGEA(buf, kk, kt)                                                                       \
  {                                                                                               \
    unsigned short* dst = HBASE(buf, 0, kk);                                                      \
    _Pragma("unroll") for (int i = 0; i < 2; ++i) {                                               \
      int c = i * 512 + tid;                                                                      \
      int r = c >> 2;                                                                             \
      int x = (c & 3) ^ ((r >> 1) & 3);                                                           \
      const unsigned short* gp = A + (size_t)(m0 + r) * 1024 + (kt) + (kk)*32 + x * 8;            \
      __builtin_amdgcn_global_load_lds((const __attribute__((address_space(1))) void*)gp,         \
                                       (__attribute__((address_space(3))) void*)&dst[c * 8],      \
                                       16, 0, 0);                                                 \
    }                                                                                             \
  }
#define STAGEB(buf, kk, kt)                                                                       \
  {                                                                                               \
    unsigned short* dst = HBASE(buf, 1, kk);                                                      \
    _Pragma("unroll") for (int i = 0; i < 2; ++i) {                                               \
      int c = (i == 0) ? tid : (512 + (tid & 255));                                               \
      int r = c >> 2;                                                                             \
      int x = (c & 3) ^ ((r >> 1) & 3);                                                           \
      const unsigned short* gp = Bw + (size_t)(n0 + r) * 1024 + (kt) + (kk)*32 + x * 8;           \
      __builtin_amdgcn_global_load_lds((const __attribute__((address_space(1))) void*)gp,         \
                                       (__attribute__((address_space(3))) void*)&dst[c * 8],      \
                                       16, 0, 0);                                                 \
    }                                                                                             \
  }

  STAGEA(0, 0, 0);
  STAGEB(0, 0, 0);
  STAGEA(0, 1, 0);
  STAGEB(0, 1, 0);

  for (int T = 0; T < 16; ++T) {
    const int buf = T & 1;
    const int last = (T == 15);
    bf16x8 bF[3];
#pragma unroll
    for (int ph = 0; ph < 4; ++ph) {
      const int kk = ph >> 1;
      const int mg = ph & 1;

      if (mg == 0) {
        if (!last) asm volatile("s_waitcnt vmcnt(4)" ::: "memory");
        else asm volatile("s_waitcnt vmcnt(0)" ::: "memory");
      }
      if (!last) {
        if (ph == 0) STAGEA(buf ^ 1, 0, (T + 1) * 64);
        if (ph == 1) STAGEB(buf ^ 1, 0, (T + 1) * 64);
        if (ph == 2) STAGEA(buf ^ 1, 1, (T + 1) * 64);
        if (ph == 3) STAGEB(buf ^ 1, 1, (T + 1) * 64);
      }
      if (mg == 0) {
        __builtin_amdgcn_sched_barrier(0);
        __builtin_amdgcn_s_barrier();
        __builtin_amdgcn_sched_barrier(0);
#pragma unroll
        for (int ni = 0; ni < 3; ++ni) {
          int rb = wn + ni * 16 + ln;
          bF[ni] = *(const bf16x8*)&HBASE(buf, 1, kk)[rb * 32 + (g ^ ((rb >> 1) & 3)) * 8];
        }
      }
      bf16x8 aF[4];
#pragma unroll
      for (int j = 0; j < 4; ++j) {
        int ra = wm + (mg * 4 + j) * 16 + ln;
        aF[j] = *(const bf16x8*)&HBASE(buf, 0, kk)[ra * 32 + (g ^ ((ra >> 1) & 3)) * 8];
      }
      __builtin_amdgcn_s_setprio(1);
#pragma unroll
      for (int j = 0; j < 4; ++j)
#pragma unroll
        for (int ni = 0; ni < 3; ++ni)
          acc[mg * 4 + j][ni] = MFMA16(aF[j], bF[ni], acc[mg * 4 + j][ni]);
      __builtin_amdgcn_s_setprio(0);
      if (ph == 3) {
        __builtin_amdgcn_sched_barrier(0);
        __builtin_amdgcn_s_barrier();
        __builtin_amdgcn_sched_barrier(0);
      }
    }
  }
#undef STAGEA
#undef STAGEB
#undef HBASE

  const int mBase = m0 + wm + g * 4;
  const int nBase = n0 + wn + ln;
#pragma unroll
  for (int mi = 0; mi < 8; ++mi) {
    int mg2 = mBase + mi * 16;
    int b = mg2 >> 11, t = mg2 & 2047;
#pragma unroll
    for (int ni = 0; ni < 3; ++ni) {
      int n = nBase + ni * 16;
      int sec = n >> 10;
      int nn = n & 1023;
      int h = nn >> 6, d = nn & 63;
      const float* bias = (sec == 0) ? b0 : (sec == 1) ? b1 : b2;
      float bvl = bias[nn];
      if (sec == 2) {
        ushort4 pk;
        pk.x = f2bf(acc[mi][ni][0] + bvl);
        pk.y = f2bf(acc[mi][ni][1] + bvl);
        pk.z = f2bf(acc[mi][ni][2] + bvl);
        pk.w = f2bf(acc[mi][ni][3] + bvl);
        *(ushort4*)&O2[((size_t)((b * 16 + h) * 64 + d)) * 2048 + t] = pk;
      } else {
        unsigned short* O = sec ? O1 : O0;
        const float sc = sec ? (0.125f * 1.44269504f) : 1.0f;
#pragma unroll
        for (int r = 0; r < 4; ++r)
          O[((size_t)(b * 16 + h) * 2048 + (t + r)) * 64 + d] = f2bf((acc[mi][ni][r] + bvl) * sc);
      }
    }
  }
}

// ---------------------------------------------------------------- proj GEMM (2-phase, R13-exact)
template <int MODE, int NX, int CPX>
__global__ void __launch_bounds__(512) gemm_big(const unsigned short* __restrict__ A,
                                                const unsigned short* __restrict__ Bw,
                                                const float* __restrict__ b0,
                                                float* __restrict__ Of) {
  extern __shared__ unsigned short lds[];

  const int tid = threadIdx.x;
  const int wid = tid >> 6;
  const int l = tid & 63;
  const int g = l >> 4;
  const int ln = l & 15;

  const int bid = blockIdx.x;
  const int swz = (bid & 7) * CPX + (bid >> 3);
  const int bx = swz % NX;
  const int by = swz / NX;
  const int m0 = by * 256;
  const int n0 = bx * 128;
  const int wm = (wid >> 1) * 64;
  const int wn = (wid & 1) * 64;

  f32x4 acc[4][4];
#pragma unroll
  for (int i = 0; i < 4; ++i)
#pragma unroll
    for (int j = 0; j < 4; ++j) acc[i][j] = (f32x4){0.f, 0.f, 0.f, 0.f};

#define STAGE_G(bufi, kt)                                                                         \
  {                                                                                               \
    unsigned short* Ad = lds + (bufi)*16384;                                                      \
    unsigned short* Bd = lds + 32768 + (bufi)*8192;                                               \
    _Pragma("unroll") for (int i = 0; i < 4; ++i) {                                               \
      int c = i * 512 + tid;                                                                      \
      int row = c >> 3;                                                                           \
      int cs = (c & 7) ^ (row & 7);                                                               \
      const unsigned short* ga = A + (size_t)(m0 + row) * 1024 + (kt) + cs * 8;                   \
      __builtin_amdgcn_global_load_lds((const __attribute__((address_space(1))) void*)ga,         \
                                       (__attribute__((address_space(3))) void*)&Ad[c * 8],       \
                                       16, 0, 0);                                                 \
    }                                                                                             \
    _Pragma("unroll") for (int i = 0; i < 2; ++i) {                                               \
      int c = i * 512 + tid;                                                                      \
      int row = c >> 3;                                                                           \
      int cs = (c & 7) ^ (row & 7);                                                               \
      const unsigned short* gb = Bw + (size_t)(n0 + row) * 1024 + (kt) + cs * 8;                  \
      __builtin_amdgcn_global_load_lds((const __attribute__((address_space(1))) void*)gb,         \
                                       (__attribute__((address_space(3))) void*)&Bd[c * 8],       \
                                       16, 0, 0);                                                 \
    }                                                                                             \
  }

  STAGE_G(0, 0);
  __syncthreads();

  for (int T = 0; T < 16; ++T) {
    const int buf = T & 1;
    if (T < 15) STAGE_G(buf ^ 1, (T + 1) * 64);

    const unsigned short* Ar = lds + buf * 16384;
    const unsigned short* Br = lds + 32768 + buf * 8192;
#pragma unroll
    for (int kk = 0; kk < 2; ++kk) {
      bf16x8 af[4], bfr[4];
#pragma unroll
      for (int mi = 0; mi < 4; ++mi) {
        int ra = wm + mi * 16 + ln;
        af[mi] = *(const bf16x8*)&Ar[ra * 64 + (((kk << 2) + g) ^ (ra & 7)) * 8];
      }
#pragma unroll
      for (int ni = 0; ni < 4; ++ni) {
        int rb = wn + ni * 16 + ln;
        bfr[ni] = *(const bf16x8*)&Br[rb * 64 + (((kk << 2) + g) ^ (rb & 7)) * 8];
      }
      __builtin_amdgcn_s_setprio(1);
#pragma unroll
      for (int mi = 0; mi < 4; ++mi)
#pragma unroll
        for (int ni = 0; ni < 4; ++ni) acc[mi][ni] = MFMA16(af[mi], bfr[ni], acc[mi][ni]);
      __builtin_amdgcn_s_setprio(0);
    }
    __syncthreads();
  }
#undef STAGE_G

  const int mBase = m0 + wm + g * 4;
  const int nBase = n0 + wn + ln;
#pragma unroll
  for (int mi = 0; mi < 4; ++mi) {
    int mg = mBase + mi * 16;
#pragma unroll
    for (int ni = 0; ni < 4; ++ni) {
      int n = nBase + ni * 16;
      float bvl = b0[n];
#pragma unroll
      for (int r = 0; r < 4; ++r) Of[(size_t)(mg + r) * 1024 + n] = acc[mi][ni][r] + bvl;
    }
  }
}

// ---------------------------------------------------------------- attention (R13-exact)
__global__ void __launch_bounds__(512) attn_kernel(const unsigned short* __restrict__ Q,
                                                   const unsigned short* __restrict__ K,
                                                   const unsigned short* __restrict__ Vt,
                                                   unsigned short* __restrict__ Y) {
  __shared__ unsigned short Ks[2][64 * 64];
  __shared__ unsigned short Vs[2][64 * 64];

  const int tid = threadIdx.x;
  const int wid = tid >> 6;          // 0..7
  const int l = tid & 63;
  const int q32 = l & 31;
  const int hi = l >> 5;
  const int bh = blockIdx.x & 63;
  const int u = blockIdx.x >> 6;     // 0..7
  const int j = (u < 4) ? u : (11 - u);
  const int qblk = (wid < 4) ? (15 - j) : j;
  const int q0w = qblk * 128 + (wid & 3) * 32;
  const int NT = 2 * (15 - j) + 2;
  const int myNt = (q0w + 95) >> 6;

  const unsigned short* Qp = Q + (size_t)bh * 2048 * 64;
  const unsigned short* Kp = K + (size_t)bh * 2048 * 64;
  const unsigned short* Vp = Vt + (size_t)bh * 64 * 2048;
  const int b = bh >> 4, h = bh & 15;

  const int srow = tid >> 3;
  const int csw = (tid & 7) ^ (srow & 7);

  bf16x8 qf[4];
#pragma unroll
  for (int kk = 0; kk < 4; ++kk)
    qf[kk] = *(const bf16x8*)&Qp[(size_t)(q0w + q32) * 64 + kk * 16 + hi * 8];

  f32x16 o0, o1;
#pragma unroll
  for (int r = 0; r < 16; ++r) { o0[r] = 0.f; o1[r] = 0.f; }
  float m = -1e30f, lst = 0.f;

#define STAGE(bufi, kk0)                                                                        \
  {                                                                                             \
    const unsigned short* gk = Kp + (size_t)((kk0) + srow) * 64 + csw * 8;                      \
    const unsigned short* gv = Vp + (size_t)srow * 2048 + (kk0) + csw * 8;                      \
    __builtin_amdgcn_global_load_lds((const __attribute__((address_space(1))) void*)gk,         \
                                     (__attribute__((address_space(3))) void*)                  \
                                         &Ks[bufi][wid * 512],                                  \
                                     16, 0, 0);                                                 \
    __builtin_amdgcn_global_load_lds((const __attribute__((address_space(1))) void*)gv,         \
                                     (__attribute__((address_space(3))) void*)                  \
                                         &Vs[bufi][wid * 512],                                  \
                                     16, 0, 0);                                                 \
  }

  int buf = 0;
  STAGE(0, 0);
  __syncthreads();

  for (int t = 0; t < NT; ++t) {
    const int k0 = t * 64;
    if (t + 1 < NT) STAGE(buf ^ 1, k0 + 64);

    if (t < myNt) {
      const int xr = q32 & 7;
      f32x16 s0, s1;
#pragma unroll
      for (int r = 0; r < 16; ++r) { s0[r] = 0.f; s1[r] = 0.f; }
      __builtin_amdgcn_s_setprio(1);
#pragma unroll
      for (int kk = 0; kk < 4; ++kk) {
        bf16x8 kf0 = *(const bf16x8*)&Ks[buf][q32 * 64 + (((kk << 1) | hi) ^ xr) * 8];
        bf16x8 kf1 = *(const bf16x8*)&Ks[buf][(32 + q32) * 64 + (((kk << 1) | hi) ^ xr) * 8];
        s0 = MFMA32(kf0, qf[kk], s0);
        s1 = MFMA32(kf1, qf[kk], s1);
      }
      __builtin_amdgcn_s_setprio(0);

      if (k0 + 63 > q0w) {
        const int qg = q0w + q32;
#pragma unroll
        for (int r = 0; r < 16; ++r) {
          int kr = (r & 3) + 8 * (r >> 2) + 4 * hi;
          if (k0 + kr > qg) s0[r] = -1e30f;
          if (k0 + 32 + kr > qg) s1[r] = -1e30f;
        }
      }

      float pm = fmaxf(fmaxf(s0[0], s0[1]), s0[2]);
#pragma unroll
      for (int r = 3; r < 15; r += 3) pm = fmaxf(fmaxf(fmaxf(s0[r], s0[r + 1]), s0[r + 2]), pm);
      pm = fmaxf(pm, s0[15]);
#pragma unroll
      for (int r = 0; r < 15; r += 3) pm = fmaxf(fmaxf(fmaxf(s1[r], s1[r + 1]), s1[r + 2]), pm);
      pm = fmaxf(pm, s1[15]);
      pm = fmaxf(pm, __shfl_xor(pm, 32));

      if (__any(pm > m + 11.0f)) {
        float mn = fmaxf(m, pm);
        float sf = exp2f_fast(m - mn);
        m = mn;
        lst *= sf;
#pragma unroll
        for (int r = 0; r < 16; ++r) {
          float sb2 = __shfl(sf, (r & 3) + 8 * (r >> 2) + 4 * hi);
          o0[r] *= sb2;
          o1[r] *= sb2;
        }
      }
      float rs = 0.f;
#pragma unroll
      for (int r = 0; r < 16; ++r) { s0[r] = exp2f_fast(s0[r] - m); rs += s0[r]; }
#pragma unroll
      for (int r = 0; r < 16; ++r) { s1[r] = exp2f_fast(s1[r] - m); rs += s1[r]; }
      rs += __shfl_xor(rs, 32);
      lst += rs;

      union { unsigned int u[4]; bf16x8 v; } pa[4];
#pragma unroll
      for (int t2 = 0; t2 < 2; ++t2) {
        const f32x16& sv = t2 ? s1 : s0;
#pragma unroll
        for (int sl = 0; sl < 2; ++sl) {
          int base = sl * 8;
          unsigned int x0 = cvtpk(sv[base + 0], sv[base + 1]);
          unsigned int x1 = cvtpk(sv[base + 2], sv[base + 3]);
          unsigned int x2 = cvtpk(sv[base + 4], sv[base + 5]);
          unsigned int x3 = cvtpk(sv[base + 6], sv[base + 7]);
          plswap(x0, x2);
          plswap(x1, x3);
          int ksg = t2 * 2 + sl;
          pa[ksg].u[0] = x0; pa[ksg].u[1] = x1; pa[ksg].u[2] = x2; pa[ksg].u[3] = x3;
        }
      }

      __builtin_amdgcn_s_setprio(1);
#pragma unroll
      for (int ksg = 0; ksg < 4; ++ksg) {
        bf16x8 v0 = *(const bf16x8*)&Vs[buf][q32 * 64 + (((ksg << 1) | hi) ^ xr) * 8];
        bf16x8 v1 = *(const bf16x8*)&Vs[buf][(32 + q32) * 64 + (((ksg << 1) | hi) ^ xr) * 8];
        o0 = MFMA32(pa[ksg].v, v0, o0);
        o1 = MFMA32(pa[ksg].v, v1, o1);
      }
      __builtin_amdgcn_s_setprio(0);
    }

    __syncthreads();
    buf ^= 1;
  }

#pragma unroll
  for (int r = 0; r < 16; ++r) {
    int qsrc = (r & 3) + 8 * (r >> 2) + 4 * hi;
    int qg = q0w + qsrc;
    float lq = __shfl(lst, qsrc);
    float inv = 1.0f / lq;
    size_t rowb = (size_t)(b * 2048 + qg) * 1024 + h * 64;
    Y[rowb + q32] = f2bf(o0[r] * inv);
    Y[rowb + 32 + q32] = f2bf(o1[r] * inv);
  }
#undef STAGE
}

// ---------------------------------------------------------------- launch
extern "C" void kernel_launch(void* const* d_in, const int* in_sizes, int n_in,
                              void* d_out, int out_size, void* d_ws, size_t ws_size,
                              hipStream_t stream) {
  const float* x = (const float*)d_in[0];
  const float* Wk = (const float*)d_in[1];
  const float* bk = (const float*)d_in[2];
  const float* Wq = (const float*)d_in[3];
  const float* bq = (const float*)d_in[4];
  const float* Wv = (const float*)d_in[5];
  const float* bv = (const float*)d_in[6];
  const float* Wp = (const float*)d_in[7];
  const float* bp = (const float*)d_in[8];
  float* out = (float*)d_out;

  char* ws = (char*)d_ws;
  unsigned short* xb    = (unsigned short*)(ws);                 // 16 MiB [8192,1024]
  unsigned short* wqkvb = (unsigned short*)(ws + 16777216);      // 6 MiB  [3072,1024]
  unsigned short* wpb   = (unsigned short*)(ws + 23068672);      // 2 MiB
  unsigned short* Qb    = (unsigned short*)(ws + 25165824);      // 16 MiB [B,H,T,D]
  unsigned short* Kb    = (unsigned short*)(ws + 41943040);      // 16 MiB [B,H,T,D]
  unsigned short* Vtb   = (unsigned short*)(ws + 58720256);      // 16 MiB [B,H,D,T]
  unsigned short* yb    = (unsigned short*)(ws + 75497472);      // 16 MiB [M,1024]
  if (ws_size < 92274688u) return;

  const int LDS_Q = 114688;  // 112 KiB (8-phase 256x192)
  const int LDS_P = 98304;   // 96 KiB (proj dbuf)
  (void)hipFuncSetAttribute((const void*)&gemm_qkv8,
                            hipFuncAttributeMaxDynamicSharedMemorySize, LDS_Q);
  (void)hipFuncSetAttribute((const void*)&gemm_big<1, 8, 32>,
                            hipFuncAttributeMaxDynamicSharedMemorySize, LDS_P);

  cvt_all<<<dim3(3072), dim3(256), 0, stream>>>(x, Wk, Wq, Wv, Wp, xb, wqkvb, wpb);

  // QKV: 32 m-tiles x 16 n-tiles (256x192) -> 512 blocks = 2 exact rounds
  gemm_qkv8<<<dim3(512), dim3(512), LDS_Q, stream>>>(xb, wqkvb, bk, bq, bv, Kb, Qb, Vtb);

  attn_kernel<<<dim3(512), dim3(512), 0, stream>>>(Qb, Kb, Vtb, yb);

  // proj: M=8192 (32), N=1024 (8) -> 256 blocks (8*32)
  gemm_big<1, 8, 32><<<dim3(256), dim3(512), LDS_P, stream>>>(yb, wpb, bp, out);
}